// Round 1
// baseline (770.661 us; speedup 1.0000x reference)
//
#include <hip/hip_runtime.h>
#include <stdint.h>

// Monarch layer: out[b, l*64+j] = bias[l*64+j] + sum_k L[j,k,l] * h1[b,k,j]
//                h1[b,k,j]      = sum_i x[b, k*64+i] * R[k,i,j]
// Fused single-pass kernel: 16 batch rows per WG, h1 in LDS, out in registers.
// Precision: bf16x3 split (AhBh + AlBh + AhBl) with fp32 accumulation.

typedef __attribute__((ext_vector_type(8))) short short8;
typedef __attribute__((ext_vector_type(4))) float f32x4;

#define LDS_SB 36                  // words per b-row: 32 k + 4 pad
#define LDS_SJ (16 * LDS_SB + 4)   // 580 words per j-plane (pad keeps banks spread)
#define LDS_WORDS (64 * LDS_SJ)    // 37120
#define LDS_BYTES (LDS_WORDS * 4)  // 148480 B  (<= 160 KiB LDS/CU)

__device__ __forceinline__ unsigned short f2bf(float f) {
    unsigned int u = __float_as_uint(f);
    u += 0x7FFFu + ((u >> 16) & 1u);   // RNE
    return (unsigned short)(u >> 16);
}
__device__ __forceinline__ float bf2f(unsigned short h) {
    return __uint_as_float(((unsigned int)h) << 16);
}
__device__ __forceinline__ f32x4 zero4() {
    f32x4 z; z[0] = 0.f; z[1] = 0.f; z[2] = 0.f; z[3] = 0.f; return z;
}
// split 8 floats into hi/lo bf16 fragments (exact split: lo = RN(v - hi))
__device__ __forceinline__ void split8(const float* v, short8& hi, short8& lo) {
#pragma unroll
    for (int e = 0; e < 8; ++e) {
        unsigned short h = f2bf(v[e]);
        hi[e] = (short)h;
        lo[e] = (short)f2bf(v[e] - bf2f(h));
    }
}

// ---- prep: R,L (fp32 [blk][row][col]) -> fragment-ordered bf16 hi/lo ----
// rt_idx(k,c,jt,lane,e) = (((k*2+c)*4+jt)*64+lane)*8+e
//   value = R[k][c*32 + (lane>>4)*8 + e][jt*16 + (lane&15)]
// lt_idx(j,g,lt,lane,e) = (((j*2+g)*4+lt)*64+lane)*8+e
//   value = L[j][g*32 + (lane>>4)*8 + e][lt*16 + (lane&15)]
__global__ void monarch_prep(const float* __restrict__ L, const float* __restrict__ R,
                             unsigned short* __restrict__ Rt_hi, unsigned short* __restrict__ Rt_lo,
                             unsigned short* __restrict__ Lt_hi, unsigned short* __restrict__ Lt_lo)
{
    int t = blockIdx.x * blockDim.x + threadIdx.x;   // 0 .. 524287
    bool isL = t >= 262144;
    int u = t & 262143;
    int e    = u & 7;
    int lane = (u >> 3) & 63;
    int tile = (u >> 9) & 3;
    int c    = (u >> 11) & 1;
    int blk  = u >> 12;                               // 0..63
    int row = c * 32 + (lane >> 4) * 8 + e;           // contraction index
    int col = tile * 16 + (lane & 15);
    const float* src = isL ? L : R;
    float v = src[blk * 4096 + row * 64 + col];
    unsigned short h  = f2bf(v);
    unsigned short lo = f2bf(v - bf2f(h));
    if (isL) { Lt_hi[u] = h; Lt_lo[u] = lo; }
    else     { Rt_hi[u] = h; Rt_lo[u] = lo; }
}

// ---- fused kernel ----
template<bool USE_WS>
__global__ __launch_bounds__(512, 2) void monarch_fused(
    const float* __restrict__ x,
    const float* __restrict__ L,
    const float* __restrict__ R,
    const float* __restrict__ bias,
    const unsigned short* __restrict__ Rt_hi,
    const unsigned short* __restrict__ Rt_lo,
    const unsigned short* __restrict__ Lt_hi,
    const unsigned short* __restrict__ Lt_lo,
    float* __restrict__ out)
{
    extern __shared__ float h1[];   // [64 j][16 b][LDS_SB] padded
    const int tid  = threadIdx.x;
    const int wid  = tid >> 6;      // 0..7
    const int lane = tid & 63;
    const int lr   = lane & 15;     // MFMA row/col sub-index
    const int lq   = lane >> 4;     // 0..3
    const long b0  = (long)blockIdx.x * 16;

    f32x4 acc[8][4];                // [jj][lt]: out[j = wid*8+jj][16b x 16l tiles]
#pragma unroll
    for (int a = 0; a < 8; ++a)
#pragma unroll
        for (int b = 0; b < 4; ++b) acc[a][b] = zero4();

    const float* xrow = x + (b0 + lr) * 4096;

#pragma unroll
    for (int g = 0; g < 2; ++g) {
        // ---------- stage 1: this wave computes k = g*32 + wid*4 + kk ----------
        // burst-issue all x loads for this group's 4 k blocks (16 x dwordx4)
        f32x4 xr[4][2][2];
#pragma unroll
        for (int kk = 0; kk < 4; ++kk) {
            const int k = g * 32 + wid * 4 + kk;
            const float* p = xrow + k * 64 + lq * 8;
#pragma unroll
            for (int c = 0; c < 2; ++c) {
                xr[kk][c][0] = *(const f32x4*)(p + c * 32);
                xr[kk][c][1] = *(const f32x4*)(p + c * 32 + 4);
            }
        }
#pragma unroll
        for (int kk = 0; kk < 4; ++kk) {
            const int k  = g * 32 + wid * 4 + kk;
            const int kl = wid * 4 + kk;         // k within group (0..31)
            f32x4 cf[4];
#pragma unroll
            for (int jt = 0; jt < 4; ++jt) cf[jt] = zero4();
#pragma unroll
            for (int c = 0; c < 2; ++c) {
                float va[8];
#pragma unroll
                for (int e = 0; e < 4; ++e) { va[e] = xr[kk][c][0][e]; va[e + 4] = xr[kk][c][1][e]; }
                short8 ah, al;
                split8(va, ah, al);
#pragma unroll
                for (int jt = 0; jt < 4; ++jt) {
                    short8 bh, bl;
                    if (USE_WS) {
                        const int idx = (((k * 2 + c) * 4 + jt) * 64 + lane) * 8;
                        bh = *(const short8*)(Rt_hi + idx);
                        bl = *(const short8*)(Rt_lo + idx);
                    } else {
                        float rv[8];
#pragma unroll
                        for (int e = 0; e < 8; ++e)
                            rv[e] = R[k * 4096 + (c * 32 + lq * 8 + e) * 64 + jt * 16 + lr];
                        split8(rv, bh, bl);
                    }
                    cf[jt] = __builtin_amdgcn_mfma_f32_16x16x32_bf16(ah, bh, cf[jt], 0, 0, 0);
                    cf[jt] = __builtin_amdgcn_mfma_f32_16x16x32_bf16(al, bh, cf[jt], 0, 0, 0);
                    cf[jt] = __builtin_amdgcn_mfma_f32_16x16x32_bf16(ah, bl, cf[jt], 0, 0, 0);
                }
            }
            // write h1 tile to LDS: C/D layout col=lane&15 (=j sub), row=(lane>>4)*4+r (=b)
#pragma unroll
            for (int jt = 0; jt < 4; ++jt) {
                const int j = jt * 16 + lr;
#pragma unroll
                for (int r = 0; r < 4; ++r) {
                    const int b = lq * 4 + r;
                    h1[j * LDS_SJ + b * LDS_SB + kl] = cf[jt][r];
                }
            }
        }
        __syncthreads();
        // ---------- stage 2: this wave handles j = wid*8 + jj ----------
#pragma unroll
        for (int jj = 0; jj < 8; ++jj) {
            const int j = wid * 8 + jj;
            const float* hp = &h1[j * LDS_SJ + lr * LDS_SB + lq * 8];
            f32x4 h0 = *(const f32x4*)(hp);
            f32x4 h4 = *(const f32x4*)(hp + 4);
            float ha[8];
#pragma unroll
            for (int e = 0; e < 4; ++e) { ha[e] = h0[e]; ha[e + 4] = h4[e]; }
            short8 ah, al;
            split8(ha, ah, al);
#pragma unroll
            for (int lt = 0; lt < 4; ++lt) {
                short8 bh, bl;
                if (USE_WS) {
                    const int idx = (((j * 2 + g) * 4 + lt) * 64 + lane) * 8;
                    bh = *(const short8*)(Lt_hi + idx);
                    bl = *(const short8*)(Lt_lo + idx);
                } else {
                    float lv[8];
#pragma unroll
                    for (int e = 0; e < 8; ++e)
                        lv[e] = L[j * 4096 + (g * 32 + lq * 8 + e) * 64 + lt * 16 + lr];
                    split8(lv, bh, bl);
                }
                acc[jj][lt] = __builtin_amdgcn_mfma_f32_16x16x32_bf16(ah, bh, acc[jj][lt], 0, 0, 0);
                acc[jj][lt] = __builtin_amdgcn_mfma_f32_16x16x32_bf16(al, bh, acc[jj][lt], 0, 0, 0);
                acc[jj][lt] = __builtin_amdgcn_mfma_f32_16x16x32_bf16(ah, bl, acc[jj][lt], 0, 0, 0);
            }
        }
        __syncthreads();
    }
    // ---------- epilogue: registers -> global (L2 merges the dword scatter) ----------
#pragma unroll
    for (int jj = 0; jj < 8; ++jj) {
        const int j = wid * 8 + jj;
#pragma unroll
        for (int lt = 0; lt < 4; ++lt) {
            const int lo_ = lt * 16 + lr;
            const float bv = bias[lo_ * 64 + j];
#pragma unroll
            for (int r = 0; r < 4; ++r) {
                const int b = lq * 4 + r;
                out[(b0 + b) * 4096 + lo_ * 64 + j] = acc[jj][lt][r] + bv;
            }
        }
    }
}

extern "C" void kernel_launch(void* const* d_in, const int* in_sizes, int n_in,
                              void* d_out, int out_size, void* d_ws, size_t ws_size,
                              hipStream_t stream)
{
    const float* x    = (const float*)d_in[0];
    const float* L    = (const float*)d_in[1];
    const float* R    = (const float*)d_in[2];
    const float* bias = (const float*)d_in[3];
    float* out = (float*)d_out;

    const size_t WS_NEED = 4ull * 262144ull * sizeof(unsigned short);  // 2 MiB
    const bool use_ws = (d_ws != nullptr) && (ws_size >= WS_NEED);

    if (use_ws) {
        unsigned short* rt_hi = (unsigned short*)d_ws;
        unsigned short* rt_lo = rt_hi + 262144;
        unsigned short* lt_hi = rt_lo + 262144;
        unsigned short* lt_lo = lt_hi + 262144;
        monarch_prep<<<2048, 256, 0, stream>>>(L, R, rt_hi, rt_lo, lt_hi, lt_lo);
        (void)hipFuncSetAttribute(reinterpret_cast<const void*>(&monarch_fused<true>),
                                  hipFuncAttributeMaxDynamicSharedMemorySize, LDS_BYTES);
        monarch_fused<true><<<1024, 512, LDS_BYTES, stream>>>(
            x, L, R, bias, rt_hi, rt_lo, lt_hi, lt_lo, out);
    } else {
        (void)hipFuncSetAttribute(reinterpret_cast<const void*>(&monarch_fused<false>),
                                  hipFuncAttributeMaxDynamicSharedMemorySize, LDS_BYTES);
        monarch_fused<false><<<1024, 512, LDS_BYTES, stream>>>(
            x, L, R, bias, nullptr, nullptr, nullptr, nullptr, out);
    }
}

// Round 2
// 567.463 us; speedup vs baseline: 1.3581x; 1.3581x over previous
//
#include <hip/hip_runtime.h>
#include <stdint.h>

// Monarch layer: out[b, l*64+j] = bias[l*64+j] + sum_k L[j,k,l] * h1[b,k,j]
//                h1[b,k,j]      = sum_i x[b, k*64+i] * R[k,i,j]
// Fused: 16 batch rows per WG (1024 thr = 16 waves), h1 in LDS, acc in regs,
// coalesced epilogue via XOR-swizzled LDS restage. bf16x3 split precision.

typedef __attribute__((ext_vector_type(8))) short short8;
typedef __attribute__((ext_vector_type(4))) float f32x4;

#define LDS_SB 36                  // words per b-row: 32 k + 4 pad
#define LDS_SJ (16 * LDS_SB + 4)   // 580 words per j-plane
#define LDS_WORDS (64 * LDS_SJ)    // 37120
#define LDS_BYTES (LDS_WORDS * 4)  // 148480 B (<= 160 KiB/CU -> 1 WG/CU)

__device__ __forceinline__ unsigned short f2bf(float f) {
    unsigned int u = __float_as_uint(f);
    u += 0x7FFFu + ((u >> 16) & 1u);   // RNE
    return (unsigned short)(u >> 16);
}
__device__ __forceinline__ float bf2f(unsigned short h) {
    return __uint_as_float(((unsigned int)h) << 16);
}
__device__ __forceinline__ f32x4 zero4() {
    f32x4 z; z[0] = 0.f; z[1] = 0.f; z[2] = 0.f; z[3] = 0.f; return z;
}
// split two f32x4 (8 contraction elems) into hi/lo bf16 fragments
__device__ __forceinline__ void split2x4(f32x4 a, f32x4 b, short8& hi, short8& lo) {
#pragma unroll
    for (int e = 0; e < 4; ++e) {
        unsigned short h = f2bf(a[e]);
        hi[e] = (short)h; lo[e] = (short)f2bf(a[e] - bf2f(h));
        unsigned short h2 = f2bf(b[e]);
        hi[e + 4] = (short)h2; lo[e + 4] = (short)f2bf(b[e] - bf2f(h2));
    }
}

// ---- prep: coalesced-read version ----
// Fragment layouts (unchanged from r1):
//  R: idx(k,c,jt,lane,e) = (((k*2+c)*4+jt)*64+lane)*8+e
//     value = R[k][c*32 + (lane>>4)*8 + e][jt*16 + (lane&15)]
//  L: idx(j,g,lt,lane,e) = (((j*2+g)*4+lt)*64+lane)*8+e
//     value = L[j][g*32 + (lane>>4)*8 + e][lt*16 + (lane&15)]
__global__ void monarch_prep(const float* __restrict__ L, const float* __restrict__ R,
                             unsigned short* __restrict__ Rt_hi, unsigned short* __restrict__ Rt_lo,
                             unsigned short* __restrict__ Lt_hi, unsigned short* __restrict__ Lt_lo)
{
    int t = blockIdx.x * blockDim.x + threadIdx.x;   // 0 .. 524287
    bool isL = t >= 262144;
    int u = t & 262143;                // linear over source: blk*4096 + row*64 + col
    int blk = u >> 12;
    int row = (u >> 6) & 63;
    int col = u & 63;
    const float* src = isL ? L : R;
    float v = src[u];                  // fully coalesced read
    int c    = row >> 5;
    int hq   = (row >> 3) & 3;
    int e    = row & 7;
    int lane = hq * 16 + (col & 15);
    int tile = col >> 4;
    int idx  = (((blk * 2 + c) * 4 + tile) * 64 + lane) * 8 + e;
    unsigned short h  = f2bf(v);
    unsigned short lo = f2bf(v - bf2f(h));
    if (isL) { Lt_hi[idx] = h; Lt_lo[idx] = lo; }
    else     { Rt_hi[idx] = h; Rt_lo[idx] = lo; }
}

// ---- fused kernel: 1024 threads = 16 waves ----
template<bool USE_WS>
__global__ __launch_bounds__(1024, 4) void monarch_fused(
    const float* __restrict__ x,
    const float* __restrict__ L,
    const float* __restrict__ R,
    const float* __restrict__ bias,
    const unsigned short* __restrict__ Rt_hi,
    const unsigned short* __restrict__ Rt_lo,
    const unsigned short* __restrict__ Lt_hi,
    const unsigned short* __restrict__ Lt_lo,
    float* __restrict__ out)
{
    extern __shared__ float h1[];   // stage: [64 j][16 b][LDS_SB]; epilogue: 8x4096 swizzled
    const int tid  = threadIdx.x;
    const int wid  = tid >> 6;      // 0..15
    const int lane = tid & 63;
    const int lr   = lane & 15;
    const int lq   = lane >> 4;     // 0..3
    const long b0  = (long)blockIdx.x * 16;

    f32x4 acc[4][4];                // [jj][lt]; j = wid*4+jj
#pragma unroll
    for (int a = 0; a < 4; ++a)
#pragma unroll
        for (int b = 0; b < 4; ++b) acc[a][b] = zero4();

    const float* xrow = x + (b0 + lr) * 4096;

#pragma unroll
    for (int g = 0; g < 2; ++g) {
        // ---------- stage 1: wave computes k = g*32 + wid*2 + {0,1} ----------
#pragma unroll
        for (int kk = 0; kk < 2; ++kk) {
            const int k  = g * 32 + wid * 2 + kk;
            const int kl = wid * 2 + kk;        // 0..31
            const float* p = xrow + k * 64 + lq * 8;
            f32x4 xa0 = *(const f32x4*)(p);
            f32x4 xa1 = *(const f32x4*)(p + 4);
            f32x4 xb0 = *(const f32x4*)(p + 32);
            f32x4 xb1 = *(const f32x4*)(p + 36);
            f32x4 cf[4];
#pragma unroll
            for (int jt = 0; jt < 4; ++jt) cf[jt] = zero4();
#pragma unroll
            for (int c = 0; c < 2; ++c) {
                short8 ah, al;
                if (c == 0) split2x4(xa0, xa1, ah, al);
                else        split2x4(xb0, xb1, ah, al);
#pragma unroll
                for (int jt = 0; jt < 4; ++jt) {
                    short8 bh, bl;
                    if (USE_WS) {
                        const int idx = (((k * 2 + c) * 4 + jt) * 64 + lane) * 8;
                        bh = *(const short8*)(Rt_hi + idx);
                        bl = *(const short8*)(Rt_lo + idx);
                    } else {
                        float rv0[4], rv1[4];
#pragma unroll
                        for (int e = 0; e < 4; ++e) {
                            rv0[e] = R[k * 4096 + (c * 32 + lq * 8 + e) * 64 + jt * 16 + lr];
                            rv1[e] = R[k * 4096 + (c * 32 + lq * 8 + 4 + e) * 64 + jt * 16 + lr];
                        }
                        f32x4 r0 = *(const f32x4*)rv0, r1 = *(const f32x4*)rv1;
                        split2x4(r0, r1, bh, bl);
                    }
                    cf[jt] = __builtin_amdgcn_mfma_f32_16x16x32_bf16(ah, bh, cf[jt], 0, 0, 0);
                    cf[jt] = __builtin_amdgcn_mfma_f32_16x16x32_bf16(al, bh, cf[jt], 0, 0, 0);
                    cf[jt] = __builtin_amdgcn_mfma_f32_16x16x32_bf16(ah, bl, cf[jt], 0, 0, 0);
                }
            }
            // h1 write: C layout col=lane&15 (j sub), row=(lane>>4)*4+r (b)
#pragma unroll
            for (int jt = 0; jt < 4; ++jt) {
                const int j = jt * 16 + lr;
#pragma unroll
                for (int r = 0; r < 4; ++r) {
                    const int b = lq * 4 + r;
                    h1[j * LDS_SJ + b * LDS_SB + kl] = cf[jt][r];
                }
            }
        }
        __syncthreads();
        // ---------- stage 2: wave handles j = wid*4 + {0..3} ----------
#pragma unroll
        for (int jj = 0; jj < 4; ++jj) {
            const int j = wid * 4 + jj;
            const float* hp = &h1[j * LDS_SJ + lr * LDS_SB + lq * 8];
            f32x4 h0 = *(const f32x4*)(hp);
            f32x4 h4 = *(const f32x4*)(hp + 4);
            short8 ah, al;
            split2x4(h0, h4, ah, al);
#pragma unroll
            for (int lt = 0; lt < 4; ++lt) {
                short8 bh, bl;
                if (USE_WS) {
                    const int idx = (((j * 2 + g) * 4 + lt) * 64 + lane) * 8;
                    bh = *(const short8*)(Lt_hi + idx);
                    bl = *(const short8*)(Lt_lo + idx);
                } else {
                    float lv0[4], lv1[4];
#pragma unroll
                    for (int e = 0; e < 4; ++e) {
                        lv0[e] = L[j * 4096 + (g * 32 + lq * 8 + e) * 64 + lt * 16 + lr];
                        lv1[e] = L[j * 4096 + (g * 32 + lq * 8 + 4 + e) * 64 + lt * 16 + lr];
                    }
                    f32x4 l0 = *(const f32x4*)lv0, l1 = *(const f32x4*)lv1;
                    split2x4(l0, l1, bh, bl);
                }
                acc[jj][lt] = __builtin_amdgcn_mfma_f32_16x16x32_bf16(ah, bh, acc[jj][lt], 0, 0, 0);
                acc[jj][lt] = __builtin_amdgcn_mfma_f32_16x16x32_bf16(al, bh, acc[jj][lt], 0, 0, 0);
                acc[jj][lt] = __builtin_amdgcn_mfma_f32_16x16x32_bf16(ah, bl, acc[jj][lt], 0, 0, 0);
            }
        }
        __syncthreads();
    }

    // ---------- epilogue: acc -> swizzled LDS -> coalesced dwordx4 stores ----------
    // logical word w = (b&7)*4096 + l*64 + j ; unit = w>>2 ; phys unit = unit ^ ((unit>>4)&15)
    const f32x4 bv = *(const f32x4*)(bias + tid * 4);
#pragma unroll
    for (int p = 0; p < 2; ++p) {
        if ((lq >> 1) == p) {
#pragma unroll
            for (int jj = 0; jj < 4; ++jj) {
                const int j = wid * 4 + jj;
#pragma unroll
                for (int lt = 0; lt < 4; ++lt) {
                    const int l = lt * 16 + lr;
#pragma unroll
                    for (int r = 0; r < 4; ++r) {
                        const int b7 = (lq & 1) * 4 + r;
                        const int w = b7 * 4096 + l * 64 + j;
                        const int unit = w >> 2;
                        const int phys = (unit ^ ((unit >> 4) & 15)) * 4 + (w & 3);
                        h1[phys] = acc[jj][lt][r];
                    }
                }
            }
        }
        __syncthreads();
#pragma unroll
        for (int it = 0; it < 8; ++it) {
            const int u = it * 1024 + tid;
            const int phys = u ^ ((u >> 4) & 15);
            f32x4 v = *(const f32x4*)(&h1[phys * 4]);
            v[0] += bv[0]; v[1] += bv[1]; v[2] += bv[2]; v[3] += bv[3];
            *(f32x4*)(&out[(b0 + p * 8 + it) * 4096 + tid * 4]) = v;
        }
        if (p == 0) __syncthreads();
    }
}

extern "C" void kernel_launch(void* const* d_in, const int* in_sizes, int n_in,
                              void* d_out, int out_size, void* d_ws, size_t ws_size,
                              hipStream_t stream)
{
    const float* x    = (const float*)d_in[0];
    const float* L    = (const float*)d_in[1];
    const float* R    = (const float*)d_in[2];
    const float* bias = (const float*)d_in[3];
    float* out = (float*)d_out;

    const size_t WS_NEED = 4ull * 262144ull * sizeof(unsigned short);  // 2 MiB
    const bool use_ws = (d_ws != nullptr) && (ws_size >= WS_NEED);

    if (use_ws) {
        unsigned short* rt_hi = (unsigned short*)d_ws;
        unsigned short* rt_lo = rt_hi + 262144;
        unsigned short* lt_hi = rt_lo + 262144;
        unsigned short* lt_lo = lt_hi + 262144;
        monarch_prep<<<2048, 256, 0, stream>>>(L, R, rt_hi, rt_lo, lt_hi, lt_lo);
        (void)hipFuncSetAttribute(reinterpret_cast<const void*>(&monarch_fused<true>),
                                  hipFuncAttributeMaxDynamicSharedMemorySize, LDS_BYTES);
        monarch_fused<true><<<1024, 1024, LDS_BYTES, stream>>>(
            x, L, R, bias, rt_hi, rt_lo, lt_hi, lt_lo, out);
    } else {
        (void)hipFuncSetAttribute(reinterpret_cast<const void*>(&monarch_fused<false>),
                                  hipFuncAttributeMaxDynamicSharedMemorySize, LDS_BYTES);
        monarch_fused<false><<<1024, 1024, LDS_BYTES, stream>>>(
            x, L, R, bias, nullptr, nullptr, nullptr, nullptr, out);
    }
}